// Round 11
// baseline (1424.292 us; speedup 1.0000x reference)
//
#include <hip/hip_runtime.h>

// StructuredLSNN v11: kill readlane delivery.
// v10 post-mortem (1107us, 649 cyc/step, VALUBusy 82%): VALU-issue-bound on
// v_readlane (1 RL per FMA in consumers = 384 cyc/step; producer RL-block
// serialized before its 256-cyc chain = ~530 cyc/step).
// Fix 1 (producer): interleave RL(k+8) after FMA(k) -> RLs issue in the
//   chain's stall slots; critical path ~290 cyc/step. 8-stagger avoids the
//   VALU->SGPR->VALU hazard.
// Fix 2 (consumer): TRANSPOSED phase A: lane=timestep, state row in 16 named
//   float4 VGPRs (16 per-lane b128/chunk); weights become wave-UNIFORM ->
//   s_load into SGPRs (SMEM pipe, zero VALU); dual-h interleaved FMA chains
//   (per-h k-order unchanged -> bit-exact). cur transposed via per-wave LDS
//   tile (row stride 68 to spread banks). Phase B: lane=h, exact LIF.
// All op orders byte-identical to the absmax=0 kernel.

#define TT 4096
#define NBATCH 256
#define HH 192
#define CS 64
#define NC (TT / CS)
#define RS 68   // padded LDS row stride (floats)

// ---- producer: readlane + FMA interleave ----
#define DS8(A0,A1,A2,A3,A4,A5,A6,A7) \
    float sreg##A0, sreg##A1, sreg##A2, sreg##A3, sreg##A4, sreg##A5, sreg##A6, sreg##A7;
#define PRL(K) sreg##K = __int_as_float(__builtin_amdgcn_readlane(__float_as_int(s_cur), K));
#define PK(Q, C, K) acc = fmaf(w##Q.C, sreg##K, acc);

#define BUILD_CHUNK(JJ, SEL) { \
    float* dst = st[SEL]; \
    const float* xc = xb + (JJ) * CS; \
    for (int q = 0; q < CS; ++q) { \
        const float xq = xc[q]; \
        DS8(0,1,2,3,4,5,6,7) DS8(8,9,10,11,12,13,14,15) \
        DS8(16,17,18,19,20,21,22,23) DS8(24,25,26,27,28,29,30,31) \
        DS8(32,33,34,35,36,37,38,39) DS8(40,41,42,43,44,45,46,47) \
        DS8(48,49,50,51,52,53,54,55) DS8(56,57,58,59,60,61,62,63) \
        PRL(0) PRL(1) PRL(2) PRL(3) PRL(4) PRL(5) PRL(6) PRL(7) \
        float acc = 0.f; \
        PK(0,x,0)  PRL(8)  PK(0,y,1)  PRL(9)  PK(0,z,2)  PRL(10) PK(0,w,3)  PRL(11) \
        PK(1,x,4)  PRL(12) PK(1,y,5)  PRL(13) PK(1,z,6)  PRL(14) PK(1,w,7)  PRL(15) \
        PK(2,x,8)  PRL(16) PK(2,y,9)  PRL(17) PK(2,z,10) PRL(18) PK(2,w,11) PRL(19) \
        PK(3,x,12) PRL(20) PK(3,y,13) PRL(21) PK(3,z,14) PRL(22) PK(3,w,15) PRL(23) \
        PK(4,x,16) PRL(24) PK(4,y,17) PRL(25) PK(4,z,18) PRL(26) PK(4,w,19) PRL(27) \
        PK(5,x,20) PRL(28) PK(5,y,21) PRL(29) PK(5,z,22) PRL(30) PK(5,w,23) PRL(31) \
        PK(6,x,24) PRL(32) PK(6,y,25) PRL(33) PK(6,z,26) PRL(34) PK(6,w,27) PRL(35) \
        PK(7,x,28) PRL(36) PK(7,y,29) PRL(37) PK(7,z,30) PRL(38) PK(7,w,31) PRL(39) \
        PK(8,x,32) PRL(40) PK(8,y,33) PRL(41) PK(8,z,34) PRL(42) PK(8,w,35) PRL(43) \
        PK(9,x,36) PRL(44) PK(9,y,37) PRL(45) PK(9,z,38) PRL(46) PK(9,w,39) PRL(47) \
        PK(10,x,40) PRL(48) PK(10,y,41) PRL(49) PK(10,z,42) PRL(50) PK(10,w,43) PRL(51) \
        PK(11,x,44) PRL(52) PK(11,y,45) PRL(53) PK(11,z,46) PRL(54) PK(11,w,47) PRL(55) \
        PK(12,x,48) PRL(56) PK(12,y,49) PRL(57) PK(12,z,50) PRL(58) PK(12,w,51) PRL(59) \
        PK(13,x,52) PRL(60) PK(13,y,53) PRL(61) PK(13,z,54) PRL(62) PK(13,w,55) PRL(63) \
        PK(14,x,56) PK(14,y,57) PK(14,z,58) PK(14,w,59) \
        PK(15,x,60) PK(15,y,61) PK(15,z,62) PK(15,w,63) \
        const float ns = __fadd_rn(acc, __fmul_rn(bi, xq)); \
        dst[q * RS + tid] = ns; \
        s_cur = ns; \
    } }

// ---- consumer phase A: dual-h chains, SGPR weights, VGPR state ----
#define PAQ(Q) \
    acca = fmaf(wa[4*Q+0], s##Q.x, acca); accb = fmaf(wb[4*Q+0], s##Q.x, accb); \
    acca = fmaf(wa[4*Q+1], s##Q.y, acca); accb = fmaf(wb[4*Q+1], s##Q.y, accb); \
    acca = fmaf(wa[4*Q+2], s##Q.z, acca); accb = fmaf(wb[4*Q+2], s##Q.z, accb); \
    acca = fmaf(wa[4*Q+3], s##Q.w, acca); accb = fmaf(wb[4*Q+3], s##Q.w, accb);

#define LIF2(CUR, TIDX) { \
    mem = __fadd_rn(__fmul_rn(0.9f, mem), CUR); \
    const float sv = (mem > 1.0f) ? 1.0f : 0.0f; \
    o[(size_t)(TIDX) * HH] = sv; \
    mem = __fmul_rn(mem, __fsub_rn(1.0f, sv)); \
    cnt += sv; }

#define CONSUME_CHUNK(JJ, SEL) { \
    const float* srow = st[SEL] + (size_t)lane * RS; \
    const float4 s0 = ((const float4*)srow)[0],  s1 = ((const float4*)srow)[1]; \
    const float4 s2 = ((const float4*)srow)[2],  s3 = ((const float4*)srow)[3]; \
    const float4 s4 = ((const float4*)srow)[4],  s5 = ((const float4*)srow)[5]; \
    const float4 s6 = ((const float4*)srow)[6],  s7 = ((const float4*)srow)[7]; \
    const float4 s8 = ((const float4*)srow)[8],  s9 = ((const float4*)srow)[9]; \
    const float4 s10 = ((const float4*)srow)[10], s11 = ((const float4*)srow)[11]; \
    const float4 s12 = ((const float4*)srow)[12], s13 = ((const float4*)srow)[13]; \
    const float4 s14 = ((const float4*)srow)[14], s15 = ((const float4*)srow)[15]; \
    for (int hh = 0; hh < 64; hh += 2) { \
        const float* wa = enc_w + (size_t)(hbase + hh) * 64; \
        const float* wb = wa + 64; \
        float acca = 0.f, accb = 0.f; \
        PAQ(0)  PAQ(1)  PAQ(2)  PAQ(3)  PAQ(4)  PAQ(5)  PAQ(6)  PAQ(7) \
        PAQ(8)  PAQ(9)  PAQ(10) PAQ(11) PAQ(12) PAQ(13) PAQ(14) PAQ(15) \
        cw[hh * RS + lane]       = __fadd_rn(acca, enc_b[hbase + hh]); \
        cw[(hh + 1) * RS + lane] = __fadd_rn(accb, enc_b[hbase + hh + 1]); \
    } \
    float* o = out1 + ((size_t)b * TT + (size_t)(JJ) * CS) * HH + hc; \
    const float* crow = cw + (size_t)lane * RS; \
    _Pragma("unroll") \
    for (int t4 = 0; t4 < 16; ++t4) { \
        const float4 c4 = ((const float4*)crow)[t4]; \
        LIF2(c4.x, 4 * t4 + 0) \
        LIF2(c4.y, 4 * t4 + 1) \
        LIF2(c4.z, 4 * t4 + 2) \
        LIF2(c4.w, 4 * t4 + 3) \
    } }

__global__ __launch_bounds__(256, 1) void lsnn_fused(
    const float* __restrict__ x,
    const float* __restrict__ A,
    const float* __restrict__ Bv,
    const float* __restrict__ enc_w,
    const float* __restrict__ enc_b,
    const float* __restrict__ ro_w,
    const float* __restrict__ ro_b,
    float* __restrict__ out0,
    float* __restrict__ out1)
{
    __shared__ __align__(16) float st[2][CS * RS];    // state tiles [q][d], padded
    __shared__ __align__(16) float curt[3 * 64 * RS]; // per-wave cur tiles [h][t], padded
    __shared__ __align__(16) float xb[TT];            // this batch's input
    __shared__ float rate[HH];

    const int tid = threadIdx.x;
    const int b = blockIdx.x;
    const int lane = tid & 63;
    const int wvu = __builtin_amdgcn_readfirstlane((int)(tid >> 6)); // uniform wave id
    const int hbase = (wvu - 1) * 64;                 // consumer waves: 0/64/128
    const int hc = hbase + lane;                      // == tid - 64 for consumers
    float* cw = curt + (size_t)(wvu > 0 ? wvu - 1 : 0) * 64 * RS;

    // ---- stage x[b][:] ----
    {
        const float4* xs = (const float4*)(x + (size_t)b * TT);
        float4* xd = (float4*)xb;
        for (int e = tid; e < TT / 4; e += 256) xd[e] = xs[e];
    }

    // ---- producer A-row in 16 named float4 registers (wave 0 only) ----
    float4 w0, w1, w2, w3, w4, w5, w6, w7, w8, w9, w10, w11, w12, w13, w14, w15;
    float bi = 0.f;
    if (tid < 64) {
        const float4* r4 = (const float4*)(A + (size_t)tid * 64);
        w0 = r4[0];   w1 = r4[1];   w2 = r4[2];   w3 = r4[3];
        w4 = r4[4];   w5 = r4[5];   w6 = r4[6];   w7 = r4[7];
        w8 = r4[8];   w9 = r4[9];   w10 = r4[10]; w11 = r4[11];
        w12 = r4[12]; w13 = r4[13]; w14 = r4[14]; w15 = r4[15];
        bi = Bv[tid];
    }

    float s_cur = 0.f;                      // producer: lane tid holds state[tid]
    float mem = 0.f, cnt = 0.f;

    // ---- pipeline: producer one chunk ahead ----
    if (tid < 64) BUILD_CHUNK(0, 0)
    __syncthreads();
    for (int j = 0; j < NC; ++j) {
        if (tid < 64) {
            if (j + 1 < NC) BUILD_CHUNK(j + 1, (j + 1) & 1)
        } else {
            CONSUME_CHUNK(j, j & 1)
        }
        __syncthreads();
    }

    // ---- rate + readout ----
    if (tid >= 64) rate[hc] = cnt * (1.0f / 4096.0f);   // exact
    __syncthreads();
    if (tid < 10) {
        float acc = 0.f;
        for (int k = 0; k < HH; ++k) acc = fmaf(ro_w[tid * HH + k], rate[k], acc);
        out0[b * 10 + tid] = __fadd_rn(acc, ro_b[tid]);
    }
}

extern "C" void kernel_launch(void* const* d_in, const int* in_sizes, int n_in,
                              void* d_out, int out_size, void* d_ws, size_t ws_size,
                              hipStream_t stream) {
    (void)out_size; (void)d_ws; (void)ws_size;
    // size-based input mapping (all seven sizes unique)
    // x:1048576  enc_w:12288  enc_b:192  ro_w:1920  ro_b:10  A:4096  B:64
    const void* px = nullptr; const void* pew = nullptr; const void* peb = nullptr;
    const void* prw = nullptr; const void* prb = nullptr; const void* pA = nullptr;
    const void* pB = nullptr;
    for (int i = 0; i < n_in; ++i) {
        switch (in_sizes[i]) {
            case 1048576: px  = d_in[i]; break;
            case 12288:   pew = d_in[i]; break;
            case 192:     peb = d_in[i]; break;
            case 1920:    prw = d_in[i]; break;
            case 10:      prb = d_in[i]; break;
            case 4096:    pA  = d_in[i]; break;
            case 64:      pB  = d_in[i]; break;
            default: break;
        }
    }
    if (!px || !pew || !peb || !prw || !prb || !pA || !pB) {
        px = d_in[0]; pew = d_in[1]; peb = d_in[2];
        prw = d_in[3]; prb = d_in[4]; pA = d_in[5]; pB = d_in[6];
    }
    const float* x     = (const float*)px;
    const float* enc_w = (const float*)pew;
    const float* enc_b = (const float*)peb;
    const float* ro_w  = (const float*)prw;
    const float* ro_b  = (const float*)prb;
    const float* A     = (const float*)pA;
    const float* Bv    = (const float*)pB;
    float* out0 = (float*)d_out;
    float* out1 = out0 + NBATCH * 10;

    lsnn_fused<<<NBATCH, 256, 0, stream>>>(x, A, Bv, enc_w, enc_b, ro_w, ro_b, out0, out1);
}

// Round 12
// 1092.993 us; speedup vs baseline: 1.3031x; 1.3031x over previous
//
#include <hip/hip_runtime.h>

// StructuredLSNN v12: v10 consumer (readlane delivery, weights VGPR-resident)
//                   + v11 producer (readlane interleaved into FMA-chain stalls).
// v11 post-mortem: consumer re-streamed enc_w from memory every chunk (~786MB
// L1/L2 traffic, latency inside the chain) -> VALUBusy 30%, 1424us. Revert
// consumer to v10 (270 issue-cyc/step, not the gate). Keep v11's producer:
// RL(k+8) issues after FMA(k) -> RL cost hides in the 4-cyc chain stalls;
// producer ~280 cyc/step (chain-latency floor 256).
// All op orders byte-identical to the absmax=0 kernel: k-sequential
// single-accumulator fmaf chains; two-rounded LIF; mem*(1-spk) NaN reset.

#define TT 4096
#define NBATCH 256
#define HH 192
#define CS 64
#define NC (TT / CS)

// ---- producer: readlane interleaved into the chain ----
#define DS8(A0,A1,A2,A3,A4,A5,A6,A7) \
    float sreg##A0, sreg##A1, sreg##A2, sreg##A3, sreg##A4, sreg##A5, sreg##A6, sreg##A7;
#define PRL(K) sreg##K = __int_as_float(__builtin_amdgcn_readlane(__float_as_int(s_cur), K));
#define PK(Q, C, K) acc = fmaf(w##Q.C, sreg##K, acc);

#define BUILD_CHUNK(JJ, SEL) { \
    float* dst = st[SEL]; \
    const float* xc = xb + (JJ) * CS; \
    for (int q = 0; q < CS; ++q) { \
        const float xq = xc[q]; \
        DS8(0,1,2,3,4,5,6,7) DS8(8,9,10,11,12,13,14,15) \
        DS8(16,17,18,19,20,21,22,23) DS8(24,25,26,27,28,29,30,31) \
        DS8(32,33,34,35,36,37,38,39) DS8(40,41,42,43,44,45,46,47) \
        DS8(48,49,50,51,52,53,54,55) DS8(56,57,58,59,60,61,62,63) \
        PRL(0) PRL(1) PRL(2) PRL(3) PRL(4) PRL(5) PRL(6) PRL(7) \
        float acc = 0.f; \
        PK(0,x,0)  PRL(8)  PK(0,y,1)  PRL(9)  PK(0,z,2)  PRL(10) PK(0,w,3)  PRL(11) \
        PK(1,x,4)  PRL(12) PK(1,y,5)  PRL(13) PK(1,z,6)  PRL(14) PK(1,w,7)  PRL(15) \
        PK(2,x,8)  PRL(16) PK(2,y,9)  PRL(17) PK(2,z,10) PRL(18) PK(2,w,11) PRL(19) \
        PK(3,x,12) PRL(20) PK(3,y,13) PRL(21) PK(3,z,14) PRL(22) PK(3,w,15) PRL(23) \
        PK(4,x,16) PRL(24) PK(4,y,17) PRL(25) PK(4,z,18) PRL(26) PK(4,w,19) PRL(27) \
        PK(5,x,20) PRL(28) PK(5,y,21) PRL(29) PK(5,z,22) PRL(30) PK(5,w,23) PRL(31) \
        PK(6,x,24) PRL(32) PK(6,y,25) PRL(33) PK(6,z,26) PRL(34) PK(6,w,27) PRL(35) \
        PK(7,x,28) PRL(36) PK(7,y,29) PRL(37) PK(7,z,30) PRL(38) PK(7,w,31) PRL(39) \
        PK(8,x,32) PRL(40) PK(8,y,33) PRL(41) PK(8,z,34) PRL(42) PK(8,w,35) PRL(43) \
        PK(9,x,36) PRL(44) PK(9,y,37) PRL(45) PK(9,z,38) PRL(46) PK(9,w,39) PRL(47) \
        PK(10,x,40) PRL(48) PK(10,y,41) PRL(49) PK(10,z,42) PRL(50) PK(10,w,43) PRL(51) \
        PK(11,x,44) PRL(52) PK(11,y,45) PRL(53) PK(11,z,46) PRL(54) PK(11,w,47) PRL(55) \
        PK(12,x,48) PRL(56) PK(12,y,49) PRL(57) PK(12,z,50) PRL(58) PK(12,w,51) PRL(59) \
        PK(13,x,52) PRL(60) PK(13,y,53) PRL(61) PK(13,z,54) PRL(62) PK(13,w,55) PRL(63) \
        PK(14,x,56) PK(14,y,57) PK(14,z,58) PK(14,w,59) \
        PK(15,x,60) PK(15,y,61) PK(15,z,62) PK(15,w,63) \
        const float ns = __fadd_rn(acc, __fmul_rn(bi, xq)); \
        dst[q * 64 + tid] = ns; \
        s_cur = ns; \
    } }

// ---- consumer: readlane extraction from one b128/step (v10) ----
#define XRL(V, Q) __int_as_float(__builtin_amdgcn_readlane(__float_as_int(V), Q))

#define CRLQ(Q) \
    const float sa##Q##0 = XRL(va.x, Q); const float sb##Q##0 = XRL(vb.x, Q); \
    const float sa##Q##1 = XRL(va.y, Q); const float sb##Q##1 = XRL(vb.y, Q); \
    const float sa##Q##2 = XRL(va.z, Q); const float sb##Q##2 = XRL(vb.z, Q); \
    const float sa##Q##3 = XRL(va.w, Q); const float sb##Q##3 = XRL(vb.w, Q);

#define CFQ(Q) \
    acc0 = fmaf(w##Q.x, sa##Q##0, acc0); acc1 = fmaf(w##Q.x, sb##Q##0, acc1); \
    acc0 = fmaf(w##Q.y, sa##Q##1, acc0); acc1 = fmaf(w##Q.y, sb##Q##1, acc1); \
    acc0 = fmaf(w##Q.z, sa##Q##2, acc0); acc1 = fmaf(w##Q.z, sb##Q##2, acc1); \
    acc0 = fmaf(w##Q.w, sa##Q##3, acc0); acc1 = fmaf(w##Q.w, sb##Q##3, acc1);

#define LIF_STEP(ACC, TOFF) { \
    const float cur = __fadd_rn(ACC, bias); \
    mem = __fadd_rn(__fmul_rn(0.9f, mem), cur); \
    const float sv = (mem > 1.0f) ? 1.0f : 0.0f; \
    o[(size_t)(t + TOFF) * HH] = sv; \
    mem = __fmul_rn(mem, __fsub_rn(1.0f, sv)); \
    cnt += sv; }

#define CONSUME_CHUNK(JJ, SEL) { \
    const float* src = st[SEL] + (tid & 15) * 4; \
    float* o = out1 + ((size_t)b * TT + (size_t)(JJ) * CS) * HH + h; \
    for (int t = 0; t < CS; t += 2) { \
        const float4 va = *(const float4*)(src + t * 64); \
        const float4 vb = *(const float4*)(src + t * 64 + 64); \
        float acc0 = 0.f, acc1 = 0.f; \
        CRLQ(0) CRLQ(1) CRLQ(2) CRLQ(3) CRLQ(4) CRLQ(5) CRLQ(6) CRLQ(7) \
        CFQ(0)  CFQ(1)  CFQ(2)  CFQ(3)  CFQ(4)  CFQ(5)  CFQ(6)  CFQ(7) \
        CRLQ(8) CRLQ(9) CRLQ(10) CRLQ(11) CRLQ(12) CRLQ(13) CRLQ(14) CRLQ(15) \
        CFQ(8)  CFQ(9)  CFQ(10)  CFQ(11)  CFQ(12)  CFQ(13)  CFQ(14)  CFQ(15) \
        LIF_STEP(acc0, 0) \
        LIF_STEP(acc1, 1) \
    } }

__global__ __launch_bounds__(256, 1) void lsnn_fused(
    const float* __restrict__ x,
    const float* __restrict__ A,
    const float* __restrict__ Bv,
    const float* __restrict__ enc_w,
    const float* __restrict__ enc_b,
    const float* __restrict__ ro_w,
    const float* __restrict__ ro_b,
    float* __restrict__ out0,
    float* __restrict__ out1)
{
    __shared__ __align__(16) float st[2][CS * 64];   // chunk state tiles [q][d]
    __shared__ __align__(16) float xb[TT];           // this batch's input
    __shared__ float rate[HH];

    const int tid = threadIdx.x;
    const int b = blockIdx.x;
    const int h = tid - 64;                 // consumer lane id 0..191 (tid>=64)

    // ---- stage x[b][:] ----
    {
        const float4* xs = (const float4*)(x + (size_t)b * TT);
        float4* xd = (float4*)xb;
        for (int e = tid; e < TT / 4; e += 256) xd[e] = xs[e];
    }

    // ---- row coefficients in 16 named float4 registers ----
    const float4* r4 = (tid < 64) ? (const float4*)(A + (size_t)tid * 64)
                                  : (const float4*)(enc_w + (size_t)h * 64);
    float4 w0 = r4[0],   w1 = r4[1],   w2 = r4[2],   w3 = r4[3];
    float4 w4 = r4[4],   w5 = r4[5],   w6 = r4[6],   w7 = r4[7];
    float4 w8 = r4[8],   w9 = r4[9],   w10 = r4[10], w11 = r4[11];
    float4 w12 = r4[12], w13 = r4[13], w14 = r4[14], w15 = r4[15];

    const float bias = (h >= 0) ? enc_b[h] : 0.f;
    const float bi   = (tid < 64) ? Bv[tid] : 0.f;

    float s_cur = 0.f;                      // producer: lane tid holds state[tid]
    float mem = 0.f, cnt = 0.f;

    // ---- pipeline: producer one chunk ahead ----
    if (tid < 64) BUILD_CHUNK(0, 0)
    __syncthreads();
    for (int j = 0; j < NC; ++j) {
        if (tid < 64) {
            if (j + 1 < NC) BUILD_CHUNK(j + 1, (j + 1) & 1)
        } else {
            CONSUME_CHUNK(j, j & 1)
        }
        __syncthreads();
    }

    // ---- rate + readout ----
    if (h >= 0) rate[h] = cnt * (1.0f / 4096.0f);   // exact (integer cnt, pow2 divide)
    __syncthreads();
    if (tid < 10) {
        float acc = 0.f;
        for (int k = 0; k < HH; ++k) acc = fmaf(ro_w[tid * HH + k], rate[k], acc);
        out0[b * 10 + tid] = __fadd_rn(acc, ro_b[tid]);
    }
}

extern "C" void kernel_launch(void* const* d_in, const int* in_sizes, int n_in,
                              void* d_out, int out_size, void* d_ws, size_t ws_size,
                              hipStream_t stream) {
    (void)out_size; (void)d_ws; (void)ws_size;
    // size-based input mapping (all seven sizes unique)
    // x:1048576  enc_w:12288  enc_b:192  ro_w:1920  ro_b:10  A:4096  B:64
    const void* px = nullptr; const void* pew = nullptr; const void* peb = nullptr;
    const void* prw = nullptr; const void* prb = nullptr; const void* pA = nullptr;
    const void* pB = nullptr;
    for (int i = 0; i < n_in; ++i) {
        switch (in_sizes[i]) {
            case 1048576: px  = d_in[i]; break;
            case 12288:   pew = d_in[i]; break;
            case 192:     peb = d_in[i]; break;
            case 1920:    prw = d_in[i]; break;
            case 10:      prb = d_in[i]; break;
            case 4096:    pA  = d_in[i]; break;
            case 64:      pB  = d_in[i]; break;
            default: break;
        }
    }
    if (!px || !pew || !peb || !prw || !prb || !pA || !pB) {
        px = d_in[0]; pew = d_in[1]; peb = d_in[2];
        prw = d_in[3]; prb = d_in[4]; pA = d_in[5]; pB = d_in[6];
    }
    const float* x     = (const float*)px;
    const float* enc_w = (const float*)pew;
    const float* enc_b = (const float*)peb;
    const float* ro_w  = (const float*)prw;
    const float* ro_b  = (const float*)prb;
    const float* A     = (const float*)pA;
    const float* Bv    = (const float*)pB;
    float* out0 = (float*)d_out;
    float* out1 = out0 + NBATCH * 10;

    lsnn_fused<<<NBATCH, 256, 0, stream>>>(x, A, Bv, enc_w, enc_b, ro_w, ro_b, out0, out1);
}

// Round 13
// 1091.820 us; speedup vs baseline: 1.3045x; 1.0011x over previous
//
#include <hip/hip_runtime.h>

// StructuredLSNN v13: 8-wave block (2 waves/SIMD) — use the idle issue slots.
// v12 post-mortem: VALU-issue-bound at 1 wave/SIMD (VALUBusy 83%, ~134 instr/step
// per wave, RL dests are SGPRs: VGPR=68/SGPR=112). Lever = occupancy, not instr mix.
// Roles (512 thr): wv0 = producer (v12 RL-interleaved chain, unchanged);
// wv1-3,5-7 = encoder GEMM, 64h x 32t each per chunk (v10 RL delivery), writing
// cur=fadd(acc,bias) to a [t][192] LDS tile (conflict-free writes AND reads);
// wv1-3 also run LIF of chunk j-1 (pipelined, cur double-buffered);
// wv4 idle so SIMD0 (round-robin pairing 0&4) is producer-only.
// ONE barrier/chunk: st[j&1] read || st[(j+1)&1] written || cur[j&1] written ||
// cur[(j-1)&1] read are pairwise disjoint.
// All op orders byte-identical to the absmax=0 kernel.

#define TT 4096
#define NBATCH 256
#define HH 192
#define CS 64
#define NC (TT / CS)

// ---- producer: readlane interleaved into the chain (v12) ----
#define DS8(A0,A1,A2,A3,A4,A5,A6,A7) \
    float sreg##A0, sreg##A1, sreg##A2, sreg##A3, sreg##A4, sreg##A5, sreg##A6, sreg##A7;
#define PRL(K) sreg##K = __int_as_float(__builtin_amdgcn_readlane(__float_as_int(s_cur), K));
#define PK(Q, C, K) acc = fmaf(w##Q.C, sreg##K, acc);

#define BUILD_CHUNK(JJ, SEL) { \
    float* dst = st[SEL]; \
    const float* xc = xb + (JJ) * CS; \
    for (int q = 0; q < CS; ++q) { \
        const float xq = xc[q]; \
        DS8(0,1,2,3,4,5,6,7) DS8(8,9,10,11,12,13,14,15) \
        DS8(16,17,18,19,20,21,22,23) DS8(24,25,26,27,28,29,30,31) \
        DS8(32,33,34,35,36,37,38,39) DS8(40,41,42,43,44,45,46,47) \
        DS8(48,49,50,51,52,53,54,55) DS8(56,57,58,59,60,61,62,63) \
        PRL(0) PRL(1) PRL(2) PRL(3) PRL(4) PRL(5) PRL(6) PRL(7) \
        float acc = 0.f; \
        PK(0,x,0)  PRL(8)  PK(0,y,1)  PRL(9)  PK(0,z,2)  PRL(10) PK(0,w,3)  PRL(11) \
        PK(1,x,4)  PRL(12) PK(1,y,5)  PRL(13) PK(1,z,6)  PRL(14) PK(1,w,7)  PRL(15) \
        PK(2,x,8)  PRL(16) PK(2,y,9)  PRL(17) PK(2,z,10) PRL(18) PK(2,w,11) PRL(19) \
        PK(3,x,12) PRL(20) PK(3,y,13) PRL(21) PK(3,z,14) PRL(22) PK(3,w,15) PRL(23) \
        PK(4,x,16) PRL(24) PK(4,y,17) PRL(25) PK(4,z,18) PRL(26) PK(4,w,19) PRL(27) \
        PK(5,x,20) PRL(28) PK(5,y,21) PRL(29) PK(5,z,22) PRL(30) PK(5,w,23) PRL(31) \
        PK(6,x,24) PRL(32) PK(6,y,25) PRL(33) PK(6,z,26) PRL(34) PK(6,w,27) PRL(35) \
        PK(7,x,28) PRL(36) PK(7,y,29) PRL(37) PK(7,z,30) PRL(38) PK(7,w,31) PRL(39) \
        PK(8,x,32) PRL(40) PK(8,y,33) PRL(41) PK(8,z,34) PRL(42) PK(8,w,35) PRL(43) \
        PK(9,x,36) PRL(44) PK(9,y,37) PRL(45) PK(9,z,38) PRL(46) PK(9,w,39) PRL(47) \
        PK(10,x,40) PRL(48) PK(10,y,41) PRL(49) PK(10,z,42) PRL(50) PK(10,w,43) PRL(51) \
        PK(11,x,44) PRL(52) PK(11,y,45) PRL(53) PK(11,z,46) PRL(54) PK(11,w,47) PRL(55) \
        PK(12,x,48) PRL(56) PK(12,y,49) PRL(57) PK(12,z,50) PRL(58) PK(12,w,51) PRL(59) \
        PK(13,x,52) PRL(60) PK(13,y,53) PRL(61) PK(13,z,54) PRL(62) PK(13,w,55) PRL(63) \
        PK(14,x,56) PK(14,y,57) PK(14,z,58) PK(14,w,59) \
        PK(15,x,60) PK(15,y,61) PK(15,z,62) PK(15,w,63) \
        const float ns = __fadd_rn(acc, __fmul_rn(bi, xq)); \
        dst[q * 64 + tid] = ns; \
        s_cur = ns; \
    } }

// ---- GEMM: readlane extraction from one b128/step (v10 pattern) ----
#define XRL(V, Q) __int_as_float(__builtin_amdgcn_readlane(__float_as_int(V), Q))

#define CRLQ(Q) \
    const float sa##Q##0 = XRL(va.x, Q); const float sb##Q##0 = XRL(vb.x, Q); \
    const float sa##Q##1 = XRL(va.y, Q); const float sb##Q##1 = XRL(vb.y, Q); \
    const float sa##Q##2 = XRL(va.z, Q); const float sb##Q##2 = XRL(vb.z, Q); \
    const float sa##Q##3 = XRL(va.w, Q); const float sb##Q##3 = XRL(vb.w, Q);

#define CFQ(Q) \
    acc0 = fmaf(w##Q.x, sa##Q##0, acc0); acc1 = fmaf(w##Q.x, sb##Q##0, acc1); \
    acc0 = fmaf(w##Q.y, sa##Q##1, acc0); acc1 = fmaf(w##Q.y, sb##Q##1, acc1); \
    acc0 = fmaf(w##Q.z, sa##Q##2, acc0); acc1 = fmaf(w##Q.z, sb##Q##2, acc1); \
    acc0 = fmaf(w##Q.w, sa##Q##3, acc0); acc1 = fmaf(w##Q.w, sb##Q##3, acc1);

#define GEMM_CHUNK(JJ, SEL, TB) { \
    const float* src = st[SEL] + (lane & 15) * 4; \
    float* cw = curt[(JJ) & 1]; \
    for (int tt = 0; tt < 32; tt += 2) { \
        const int t = (TB) + tt; \
        const float4 va = *(const float4*)(src + t * 64); \
        const float4 vb = *(const float4*)(src + t * 64 + 64); \
        float acc0 = 0.f, acc1 = 0.f; \
        CRLQ(0) CRLQ(1) CRLQ(2) CRLQ(3) CRLQ(4) CRLQ(5) CRLQ(6) CRLQ(7) \
        CFQ(0)  CFQ(1)  CFQ(2)  CFQ(3)  CFQ(4)  CFQ(5)  CFQ(6)  CFQ(7) \
        CRLQ(8) CRLQ(9) CRLQ(10) CRLQ(11) CRLQ(12) CRLQ(13) CRLQ(14) CRLQ(15) \
        CFQ(8)  CFQ(9)  CFQ(10)  CFQ(11)  CFQ(12)  CFQ(13)  CFQ(14)  CFQ(15) \
        cw[t * HH + hw]       = __fadd_rn(acc0, bias); \
        cw[(t + 1) * HH + hw] = __fadd_rn(acc1, bias); \
    } }

// ---- LIF scan over a finished cur tile (waves 1-3, lane = h) ----
#define LIF_CHUNK(JJ) { \
    const float* cr = curt[(JJ) & 1] + h; \
    float* o = out1 + ((size_t)b * TT + (size_t)(JJ) * CS) * HH + h; \
    _Pragma("unroll 8") \
    for (int t = 0; t < CS; ++t) { \
        const float cur = cr[t * HH]; \
        mem = __fadd_rn(__fmul_rn(0.9f, mem), cur); \
        const float sv = (mem > 1.0f) ? 1.0f : 0.0f; \
        o[(size_t)t * HH] = sv; \
        mem = __fmul_rn(mem, __fsub_rn(1.0f, sv)); \
        cnt += sv; \
    } }

__global__ __launch_bounds__(512, 2) void lsnn_fused(
    const float* __restrict__ x,
    const float* __restrict__ A,
    const float* __restrict__ Bv,
    const float* __restrict__ enc_w,
    const float* __restrict__ enc_b,
    const float* __restrict__ ro_w,
    const float* __restrict__ ro_b,
    float* __restrict__ out0,
    float* __restrict__ out1)
{
    __shared__ __align__(16) float st[2][CS * 64];    // state tiles [q][d]   32K
    __shared__ __align__(16) float curt[2][CS * HH];  // cur tiles [t][h]     96K
    __shared__ __align__(16) float xb[TT];            // input                16K
    __shared__ float rate[HH];

    const int tid = threadIdx.x;
    const int b = blockIdx.x;
    const int lane = tid & 63;
    const int wv = tid >> 6;                // 0..7

    // ---- stage x[b][:] ----
    {
        const float4* xs = (const float4*)(x + (size_t)b * TT);
        float4* xd = (float4*)xb;
        for (int e = tid; e < TT / 4; e += 512) xd[e] = xs[e];
    }

    // ---- roles ----
    // wv0: producer. wv1-3,5-7: GEMM (hbase x t-half). wv1-3: +LIF. wv4: idle.
    const int hbase = (wv == 1 || wv == 5) ? 0 : ((wv == 2 || wv == 6) ? 64 : 128);
    const int hw = hbase + lane;            // GEMM output row (always < 192)
    const int tb = (wv >= 5) ? 32 : 0;      // GEMM t-half
    const int h = tid - 64;                 // LIF row for waves 1-3

    // ---- weights: A row (wv0) / enc_w row (others) in named float4 regs ----
    const float4* r4 = (wv == 0) ? (const float4*)(A + (size_t)lane * 64)
                                 : (const float4*)(enc_w + (size_t)hw * 64);
    float4 w0 = r4[0],   w1 = r4[1],   w2 = r4[2],   w3 = r4[3];
    float4 w4 = r4[4],   w5 = r4[5],   w6 = r4[6],   w7 = r4[7];
    float4 w8 = r4[8],   w9 = r4[9],   w10 = r4[10], w11 = r4[11];
    float4 w12 = r4[12], w13 = r4[13], w14 = r4[14], w15 = r4[15];

    const float bias = enc_b[hw];           // used by GEMM waves only
    const float bi   = (wv == 0) ? Bv[lane] : 0.f;

    float s_cur = 0.f;                      // producer state (lane = d index)
    float mem = 0.f, cnt = 0.f;             // LIF state (waves 1-3)

    __syncthreads();                        // xb staged
    if (wv == 0) BUILD_CHUNK(0, 0)
    __syncthreads();                        // chunk 0 ready

    for (int j = 0; j < NC; ++j) {
        if (wv == 0) {
            if (j + 1 < NC) BUILD_CHUNK(j + 1, (j + 1) & 1)
        } else if (wv != 4) {
            GEMM_CHUNK(j, j & 1, tb)
        }
        if (wv >= 1 && wv <= 3 && j > 0) LIF_CHUNK(j - 1)
        __syncthreads();
    }

    // ---- epilogue: last LIF + rate + readout ----
    if (wv >= 1 && wv <= 3) {
        LIF_CHUNK(NC - 1)
        rate[h] = cnt * (1.0f / 4096.0f);   // exact (integer cnt, pow2 divide)
    }
    __syncthreads();
    if (tid < 10) {
        float acc = 0.f;
        for (int k = 0; k < HH; ++k) acc = fmaf(ro_w[tid * HH + k], rate[k], acc);
        out0[b * 10 + tid] = __fadd_rn(acc, ro_b[tid]);
    }
}

extern "C" void kernel_launch(void* const* d_in, const int* in_sizes, int n_in,
                              void* d_out, int out_size, void* d_ws, size_t ws_size,
                              hipStream_t stream) {
    (void)out_size; (void)d_ws; (void)ws_size;
    // size-based input mapping (all seven sizes unique)
    // x:1048576  enc_w:12288  enc_b:192  ro_w:1920  ro_b:10  A:4096  B:64
    const void* px = nullptr; const void* pew = nullptr; const void* peb = nullptr;
    const void* prw = nullptr; const void* prb = nullptr; const void* pA = nullptr;
    const void* pB = nullptr;
    for (int i = 0; i < n_in; ++i) {
        switch (in_sizes[i]) {
            case 1048576: px  = d_in[i]; break;
            case 12288:   pew = d_in[i]; break;
            case 192:     peb = d_in[i]; break;
            case 1920:    prw = d_in[i]; break;
            case 10:      prb = d_in[i]; break;
            case 4096:    pA  = d_in[i]; break;
            case 64:      pB  = d_in[i]; break;
            default: break;
        }
    }
    if (!px || !pew || !peb || !prw || !prb || !pA || !pB) {
        px = d_in[0]; pew = d_in[1]; peb = d_in[2];
        prw = d_in[3]; prb = d_in[4]; pA = d_in[5]; pB = d_in[6];
    }
    const float* x     = (const float*)px;
    const float* enc_w = (const float*)pew;
    const float* enc_b = (const float*)peb;
    const float* ro_w  = (const float*)prw;
    const float* ro_b  = (const float*)prb;
    const float* A     = (const float*)pA;
    const float* Bv    = (const float*)pB;
    float* out0 = (float*)d_out;
    float* out1 = out0 + NBATCH * 10;

    lsnn_fused<<<NBATCH, 512, 0, stream>>>(x, A, Bv, enc_w, enc_b, ro_w, ro_b, out0, out1);
}